// Round 4
// baseline (574.461 us; speedup 1.0000x reference)
//
#include <hip/hip_runtime.h>
#include <hip/hip_cooperative_groups.h>
#include <hip/hip_bf16.h>
#include <algorithm>
#include <cmath>

namespace cg = cooperative_groups;

#define HH 96
#define WW 96
#define CC 21
#define NN (HH*WW)          // 9216
#define NELEM (NN*CC)       // 193536
#define RS 20
#define NPAR (2*CC + CC*CC)
#define L2E 1.4426950408889634f
#define NBB (36*24)
#define NBLUR (CC*8)        // 168 blur items
#define SROWS 12
#define TRUNC2 1225         // 35^2
#define BLURKEY 0x10000
#define NUPD (NN/128)       // 72 update chunks

typedef short bf16x8 __attribute__((ext_vector_type(8)));
typedef float f32x16 __attribute__((ext_vector_type(16)));

__device__ __forceinline__ float fexp2(float x) { return __builtin_amdgcn_exp2f(x); }
__device__ __forceinline__ float fexp(float x)  { return __builtin_amdgcn_exp2f(x * L2E); }

__device__ __forceinline__ short f2b(float f) {
    __hip_bfloat16 h = __float2bfloat16(f);
    short s; __builtin_memcpy(&s, &h, 2); return s;
}

// Single persistent cooperative kernel: sniff -> prep -> 5x(work -> update).
// Inner loop bodies identical to the R3 multi-launch version (isolates the
// structural change and makes this the top dispatch for rocprof).
__global__ __launch_bounds__(256, 3) void k_all(
    const void* __restrict__ u, const void* __restrict__ img,
    const void* __restrict__ wS, const void* __restrict__ wB,
    const void* __restrict__ compat, void* __restrict__ out,
    float* __restrict__ uf, float* __restrict__ featx, float* __restrict__ par,
    float* __restrict__ bil, __hip_bfloat16* __restrict__ pTg,
    float* __restrict__ s2T, int* __restrict__ flag32,
    const int* __restrict__ tab, int ntab)
{
    __shared__ float smem[6176];             // bilateral 3072 / blur 6165 / update 493
    cg::grid_group grid = cg::this_grid();
    const int tid = threadIdx.x;
    const int bid0 = blockIdx.x;
    const int gsz = gridDim.x;

    // ---------- phase 0: dtype sniff (bf16 never has exp=0xFF halves) ----------
    if (bid0 < 32) {
        int* sf = (int*)smem;
        if (tid == 0) *sf = 0;
        __syncthreads();
        const unsigned short* u16 = (const unsigned short*)u;
        const int base = bid0 * (NELEM/32);
        int found = 0;
        for (int i = base + tid; i < base + NELEM/32; i += 256)
            if ((u16[i] & 0x7F80u) == 0x7F80u) found = 1;
        if (found) *sf = 1;
        __syncthreads();
        if (tid == 0) flag32[bid0] = *sf;
    }
    grid.sync();

    int f = 0;
    #pragma unroll
    for (int i = 0; i < 32; i++) f |= flag32[i];   // uniform scalar loads

    // ---------- phase 1: prep (featx, params, softmax(u) -> pT, zero bil) ----------
    for (int ch = bid0; ch < 36; ch += gsz) {
        const int n = ch * 256 + tid;
        if (ch == 0) {
            for (int i = tid; i < NPAR; i += 256) {
                const void* src; int j;
                if (i < CC)        { src = wS;     j = i; }
                else if (i < 2*CC) { src = wB;     j = i - CC; }
                else               { src = compat; j = i - 2*CC; }
                par[i] = f ? ((const float*)src)[j]
                           : __bfloat162float(((const __hip_bfloat16*)src)[j]);
            }
        }
        {
            float c0, c1, c2;
            if (f) { const float* p = (const float*)img;
                     c0 = p[3*n]; c1 = p[3*n+1]; c2 = p[3*n+2]; }
            else   { const __hip_bfloat16* p = (const __hip_bfloat16*)img;
                     c0 = __bfloat162float(p[3*n]); c1 = __bfloat162float(p[3*n+1]);
                     c2 = __bfloat162float(p[3*n+2]); }
            float ym = (float)(n / WW), xm = (float)(n % WW);
            const float sc_ = 0.15014029f;   // sqrt(2*L2E/128)
            const float cf  = 9.6089787f;    // sqrt(64*L2E)
            featx[8*n+0] = -L2E * (fmaf(ym, ym, xm*xm) * 0.0078125f
                                   + 32.f * (c0*c0 + c1*c1 + c2*c2));
            featx[8*n+1] = sc_*ym; featx[8*n+2] = sc_*xm;
            featx[8*n+3] = cf*c0;  featx[8*n+4] = cf*c1;  featx[8*n+5] = cf*c2;
            featx[8*n+6] = 0.f;    featx[8*n+7] = 0.f;
        }
        float v[CC]; float mx = -1e30f;
        #pragma unroll
        for (int c = 0; c < CC; c++) {
            float uv = f ? ((const float*)u)[n*CC+c]
                         : __bfloat162float(((const __hip_bfloat16*)u)[n*CC+c]);
            uf[n*CC+c] = uv; v[c] = uv; mx = fmaxf(mx, uv);
        }
        float s = 0.f;
        #pragma unroll
        for (int c = 0; c < CC; c++) { v[c] = fexp(v[c]-mx); s += v[c]; }
        float inv = 1.f/s;
        #pragma unroll
        for (int c = 0; c < CC; c++) {
            pTg[(size_t)c*NN+n] = __float2bfloat16(v[c]*inv);
            bil[(size_t)c*NN+n] = 0.f;
        }
    }
    grid.sync();

    // ---------- 5 CRF iterations ----------
    for (int it = 0; it < 5; it++) {
        // ----- work phase: bilateral MFMA items + blur items (LPT table) -----
        for (int w = bid0; w < ntab; w += gsz) {
            __syncthreads();                 // smem reuse guard across items
            const int item = tab[w];
            if (item < BLURKEY) {
                float* lds_h = smem;
                const int wv = tid >> 6, lane = tid & 63;
                const int quad = lane >> 5, lid = lane & 31;
                const int nt = item >> 5, mc = item & 31;
                const int ny0 = (nt/6)*16, nx0 = (nt%6)*16;
                const int my0 = (mc&3)*24, mx0 = (mc>>2)*16;
                const int dx = (mx0 > nx0+15) ? mx0-(nx0+15)
                             : ((nx0 > mx0+15) ? nx0-(mx0+15) : 0);
                const int lim = TRUNC2 - dx*dx;          // >= 0 (host-culled)
                int T = (int)sqrtf((float)lim);
                T -= (T*T > lim);
                T += ((T+1)*(T+1) <= lim);
                int blo = ny0 - T - my0;      blo = blo < 0 ? 0 : blo;
                int bhi = ny0 + 15 + T - my0; bhi = bhi > 23 ? 23 : bhi;
                {   // stage featx rows blo..bhi
                    float4* dst = (float4*)lds_h;
                    for (int i = blo*32 + tid; i < (bhi+1)*32; i += 256) {
                        const int seg = i >> 5, off = i & 31;
                        dst[i] = ((const float4*)(featx +
                                  (size_t)((my0+seg)*WW + mx0)*8))[off];
                    }
                }
                __syncthreads();
                const int by0 = ny0 + 4*wv;
                int lo = by0 - T - my0;     lo = lo < 0 ? 0 : lo;
                int hi = by0 + 3 + T - my0; hi = hi > 23 ? 23 : hi;
                if (lo <= hi) {              // wave-uniform
                    const int row = lid >> 4, col = lid & 15;
                    const int n0 = (by0+row)*WW + nx0 + col;
                    const int n1 = n0 + 2*WW;
                    const float4 g0a = *(const float4*)(featx + (size_t)n0*8);
                    const float4 g0b = *(const float4*)(featx + (size_t)n0*8 + 4);
                    const float4 g1a = *(const float4*)(featx + (size_t)n1*8);
                    const float4 g1b = *(const float4*)(featx + (size_t)n1*8 + 4);
                    f32x16 acc0, acc1;
                    #pragma unroll
                    for (int r = 0; r < 16; r++) { acc0[r]=0.f; acc1[r]=0.f; }
                    int mg = (my0+lo)*WW + mx0 + quad*8;
                    #pragma unroll 1
                    for (int step = lo; step <= hi; step++, mg += WW) {
                        bf16x8 afrag = *(const bf16x8*)(pTg + (size_t)lid*NN + mg);
                        const float* h = lds_h + (step*16 + quad*8)*8;
                        float kb0[8], kb1[8];
                        #pragma unroll
                        for (int j = 0; j < 8; j++) {
                            float4 ha = *(const float4*)(h + j*8);
                            float4 hb = *(const float4*)(h + j*8 + 4);
                            float s0 = g0a.x + ha.x;
                            s0 = fmaf(g0a.y,ha.y,s0); s0 = fmaf(g0a.z,ha.z,s0);
                            s0 = fmaf(g0a.w,ha.w,s0); s0 = fmaf(g0b.x,hb.x,s0);
                            s0 = fmaf(g0b.y,hb.y,s0);
                            kb0[j] = fexp2(s0);
                            float s1 = g1a.x + ha.x;
                            s1 = fmaf(g1a.y,ha.y,s1); s1 = fmaf(g1a.z,ha.z,s1);
                            s1 = fmaf(g1a.w,ha.w,s1); s1 = fmaf(g1b.x,hb.x,s1);
                            s1 = fmaf(g1b.y,hb.y,s1);
                            kb1[j] = fexp2(s1);
                        }
                        bf16x8 b0, b1;
                        #pragma unroll
                        for (int j = 0; j < 8; j++) { b0[j]=f2b(kb0[j]); b1[j]=f2b(kb1[j]); }
                        acc0 = __builtin_amdgcn_mfma_f32_32x32x16_bf16(afrag,b0,acc0,0,0,0);
                        acc1 = __builtin_amdgcn_mfma_f32_32x32x16_bf16(afrag,b1,acc1,0,0,0);
                    }
                    #pragma unroll
                    for (int r = 0; r < 16; r++) {
                        int c = (r&3) + 8*(r>>2) + 4*quad;
                        if (c < CC) {
                            atomicAdd(&bil[(size_t)c*NN + n0], acc0[r]);
                            atomicAdd(&bil[(size_t)c*NN + n1], acc1[r]);
                        }
                    }
                }
            } else {
                // spatial blur: one (channel, 12-row strip) item
                float* A   = smem;           // up to 52 rows x 96
                float* B2  = smem + 4992;    // 12 x 96
                float* w_s = smem + 6144;    // 21 weights
                const int b2 = item - BLURKEY;
                const int c = b2 % CC;
                const int strip = b2 / CC;
                const int y0 = strip * SROWS;
                const int ylo = (y0-RS < 0) ? 0 : y0-RS;
                const int yhi = (y0+SROWS-1+RS > HH-1) ? HH-1 : y0+SROWS-1+RS;
                const int nrows = yhi - ylo + 1;
                if (tid <= RS) w_s[tid] = fexp2(-(float)(tid*tid)*(L2E/18.f));
                const __hip_bfloat16* src = pTg + (size_t)c*NN + ylo*WW;
                for (int i = tid; i < nrows*WW; i += 256)
                    A[i] = __bfloat162float(src[i]);
                __syncthreads();
                for (int i = tid; i < SROWS*WW; i += 256) {
                    const int yo = y0 + i/WW;
                    const int x  = i % WW;
                    float acc = A[(yo-ylo)*WW + x];
                    #pragma unroll
                    for (int d = 1; d <= RS; d++) {
                        float s = 0.f;
                        if (yo-d >= 0) s += A[(yo-d-ylo)*WW + x];
                        if (yo+d < HH) s += A[(yo+d-ylo)*WW + x];
                        acc = fmaf(w_s[d], s, acc);
                    }
                    B2[i] = acc;
                }
                __syncthreads();
                for (int i = tid; i < SROWS*WW; i += 256) {
                    const int r = i/WW, x = i%WW;
                    float acc = B2[i];
                    #pragma unroll
                    for (int d = 1; d <= RS; d++) {
                        float s = 0.f;
                        if (x-d >= 0) s += B2[r*WW + x-d];
                        if (x+d < WW) s += B2[r*WW + x+d];
                        acc = fmaf(w_s[d], s, acc);
                    }
                    s2T[(size_t)c*NN + (y0+r)*WW + x] = acc;
                }
            }
        }
        grid.sync();

        // ----- update phase: message combine + compat + q-update + softmax -----
        const int last = (it == 4);
        for (int w = bid0; w < NUPD; w += gsz) {
            __syncthreads();                 // smem reuse guard
            float* sc  = smem;               // [441]+pad
            float* sws = smem + 448;
            float* swb = smem + 472;
            for (int i = tid; i < CC*CC; i += 256) sc[i] = par[2*CC + i];
            if (tid == 0) sc[CC*CC] = 0.f;
            if (tid < CC) { sws[tid] = par[tid]; swb[tid] = par[CC+tid]; }
            __syncthreads();
            const int half = tid & 1;
            const int n = w*128 + (tid >> 1);
            float msg[11];
            #pragma unroll
            for (int k = 0; k < 11; k++) {
                const int cp = 2*k + half;
                if (cp < CC) {
                    msg[k] = fmaf(s2T[(size_t)cp*NN+n], sws[cp],
                                  bil[(size_t)cp*NN+n] * swb[cp]);
                    bil[(size_t)cp*NN+n] = 0.f;
                } else msg[k] = 0.f;
            }
            float pw[CC];
            #pragma unroll
            for (int c = 0; c < CC; c++) {
                float a = msg[0] * sc[c*CC + half];
                #pragma unroll
                for (int k = 1; k < 11; k++)
                    a = fmaf(msg[k], sc[c*CC + 2*k + half], a);
                pw[c] = a;
            }
            #pragma unroll
            for (int c = 0; c < CC; c++)
                pw[c] += __shfl_xor(pw[c], 1, 64);
            float qv[CC]; float mx = -1e30f;
            #pragma unroll
            for (int c = 0; c < CC; c++) {
                qv[c] = uf[(size_t)n*CC+c] - pw[c];
                mx = fmaxf(mx, qv[c]);
            }
            if (last) {
                #pragma unroll
                for (int k = 0; k < 11; k++) {
                    const int ce = 2*k, co = (k < 10) ? 2*k+1 : 0;
                    float v = half ? qv[co] : qv[ce];
                    const int c = 2*k + half;
                    if (c < CC) {
                        if (f) ((float*)out)[(size_t)n*CC+c] = v;
                        else ((__hip_bfloat16*)out)[(size_t)n*CC+c] = __float2bfloat16(v);
                    }
                }
            } else {
                float ex[11]; float ssum = 0.f;
                #pragma unroll
                for (int k = 0; k < 11; k++) {
                    const int ce = 2*k, co = (k < 10) ? 2*k+1 : 0;
                    float v = half ? qv[co] : qv[ce];
                    float e = fexp(v - mx);
                    if (2*k + half < CC) ssum += e;
                    ex[k] = e;
                }
                ssum += __shfl_xor(ssum, 1, 64);
                const float inv = 1.f/ssum;
                #pragma unroll
                for (int k = 0; k < 11; k++) {
                    const int c = 2*k + half;
                    if (c < CC) pTg[(size_t)c*NN+n] = __float2bfloat16(ex[k]*inv);
                }
            }
        }
        if (it != 4) grid.sync();
    }
}

extern "C" void kernel_launch(void* const* d_in, const int* in_sizes, int n_in,
                              void* d_out, int out_size, void* d_ws, size_t ws_size,
                              hipStream_t stream)
{
    // ---- static work table (compile-time geometry): culled survivors, LPT order
    static int h_tab[NBB + NBLUR];
    static int h_n = 0;
    static int G = 0;
    if (h_n == 0) {
        struct It { int key; int cost; };
        static It its[NBB + NBLUR];
        int m = 0;
        for (int nt = 0; nt < 36; nt++)
            for (int mc = 0; mc < 24; mc++) {
                const int ny0 = (nt/6)*16, nx0 = (nt%6)*16;
                const int my0 = (mc&3)*24, mx0 = (mc>>2)*16;
                const int dx = (mx0 > nx0+15) ? mx0-(nx0+15)
                             : ((nx0 > mx0+15) ? nx0-(mx0+15) : 0);
                const int lim = TRUNC2 - dx*dx;
                if (lim < 0) continue;
                int T = (int)std::sqrt((double)lim);
                while (T*T > lim) T--;
                while ((T+1)*(T+1) <= lim) T++;
                int cost = 0;
                for (int wv = 0; wv < 4; wv++) {
                    const int by0 = ny0 + 4*wv;
                    int lo = by0 - T - my0;     if (lo < 0)  lo = 0;
                    int hi = by0 + 3 + T - my0; if (hi > 23) hi = 23;
                    if (lo <= hi) cost += hi - lo + 1;
                }
                if (cost == 0) continue;
                its[m].key = (nt << 5) | mc; its[m].cost = cost; m++;
            }
        for (int b = 0; b < NBLUR; b++) { its[m].key = BLURKEY + b; its[m].cost = 20; m++; }
        std::sort(its, its + m, [](const It& a, const It& b) { return a.cost > b.cost; });
        for (int i = 0; i < m; i++) h_tab[i] = its[i].key;
        h_n = m;
    }
    if (G == 0) {
        int nb = 0;
        if (hipOccupancyMaxActiveBlocksPerMultiprocessor(&nb, k_all, 256, 0) != hipSuccess
            || nb < 1) nb = 3;                       // launch_bounds guarantees 3
        long cap = (long)nb * 256;                   // 256 CUs on MI355X
        G = (int)std::min<long>(cap, (long)h_n);
        if (G < NUPD) G = NUPD;                      // >= 72 (and >= 32 for sniff)
    }

    float* ws = (float*)d_ws;
    int*   flag32 = (int*)ws;                    // [0..32)
    float* par    = ws + 32;                     // 483 used
    float* featx  = ws + 544;                    // NN*8 = 73728 floats
    __hip_bfloat16* pT = (__hip_bfloat16*)(ws + 74272);   // 32*NN bf16 = 147456 floats
    float* uf  = ws + 74272 + 147456;            // NELEM  (= ws+221728)
    float* s2T = uf + NELEM;
    float* bil = s2T + NELEM;
    int*   d_tab = (int*)(bil + NELEM);

    hipMemcpyAsync(d_tab, h_tab, h_n * sizeof(int), hipMemcpyHostToDevice, stream);

    const void* a_u   = d_in[0];
    const void* a_img = d_in[1];
    const void* a_wS  = d_in[2];
    const void* a_wB  = d_in[3];
    const void* a_cm  = d_in[4];
    void*  a_out = d_out;
    float* a_uf = uf; float* a_fx = featx; float* a_par = par;
    float* a_bil = bil; __hip_bfloat16* a_pT = pT; float* a_s2T = s2T;
    int* a_flag = flag32; const int* a_tab = d_tab; int a_n = h_n;
    void* args[] = { &a_u, &a_img, &a_wS, &a_wB, &a_cm, &a_out,
                     &a_uf, &a_fx, &a_par, &a_bil, &a_pT, &a_s2T,
                     &a_flag, &a_tab, &a_n };

    hipLaunchCooperativeKernel((void*)k_all, dim3(G), dim3(256), args, 0, stream);
}

// Round 5
// 238.764 us; speedup vs baseline: 2.4060x; 2.4060x over previous
//
#include <hip/hip_runtime.h>
#include <hip/hip_bf16.h>
#include <algorithm>
#include <cmath>

#define HH 96
#define WW 96
#define CC 21
#define NN (HH*WW)          // 9216
#define NELEM (NN*CC)       // 193536
#define RS 20
#define NPAR (2*CC + CC*CC)
#define L2E 1.4426950408889634f
#define NBB (36*24)
#define NBLUR (CC*8)        // 168 blur items
#define SROWS 12
#define TRUNC2 1225         // 35^2
#define BLURKEY 0x10000

typedef short bf16x8 __attribute__((ext_vector_type(8)));
typedef float f32x16 __attribute__((ext_vector_type(16)));

__device__ __forceinline__ float fexp2(float x) { return __builtin_amdgcn_exp2f(x); }
__device__ __forceinline__ float fexp(float x)  { return __builtin_amdgcn_exp2f(x * L2E); }

__device__ __forceinline__ short f2b(float f) {
    __hip_bfloat16 h = __float2bfloat16(f);
    short s; __builtin_memcpy(&s, &h, 2); return s;
}

// ---- dtype sniff: bf16 data never contains exp=0xFF bit patterns.
__global__ void k_sniff(const unsigned short* __restrict__ u16, int* __restrict__ flag32) {
    __shared__ int sfound;
    if (threadIdx.x == 0) sfound = 0;
    __syncthreads();
    const int base = blockIdx.x * (NELEM/32);
    int found = 0;
    for (int i = base + threadIdx.x; i < base + NELEM/32; i += 256) {
        unsigned v = u16[i];
        if ((v & 0x7F80u) == 0x7F80u) found = 1;
    }
    if (found) sfound = 1;
    __syncthreads();
    if (threadIdx.x == 0) flag32[blockIdx.x] = sfound;
}

__device__ __forceinline__ int rdflag(const int* __restrict__ flag32) {
    int f = 0;
    #pragma unroll
    for (int i = 0; i < 32; i++) f |= flag32[i];
    return f;
}

// geometry helpers shared by both work kernels
__device__ __forceinline__ void item_geom(int item, int& ny0, int& nx0, int& my0,
                                          int& mx0, int& dx, int& T) {
    const int nt = item >> 5, mc = item & 31;
    ny0 = (nt / 6) * 16; nx0 = (nt % 6) * 16;
    my0 = (mc & 3) * 24; mx0 = (mc >> 2) * 16;
    dx = (mx0 > nx0 + 15) ? mx0 - (nx0 + 15)
       : ((nx0 > mx0 + 15) ? nx0 - (mx0 + 15) : 0);
    const int lim = TRUNC2 - dx * dx;          // >= 0 (host-culled)
    T = (int)sqrtf((float)lim);
    T -= (T * T > lim);
    T += ((T + 1) * (T + 1) <= lim);
}

__device__ __forceinline__ void wave_range(int ny0, int my0, int T, int wv,
                                           int& lo, int& hi) {
    const int by0 = ny0 + 4 * wv;
    lo = by0 - T - my0;     lo = lo < 0 ? 0 : lo;
    hi = by0 + 3 + T - my0; hi = hi > 23 ? 23 : hi;
}

// Fused prep (unchanged from R3)
__global__ __launch_bounds__(256) void k_prep(
    const void* __restrict__ u, const void* __restrict__ img,
    const void* __restrict__ wS, const void* __restrict__ wB,
    const void* __restrict__ compat, const int* __restrict__ flag32,
    float* __restrict__ uf, float* __restrict__ featx, float* __restrict__ par,
    float* __restrict__ bil, __hip_bfloat16* __restrict__ pT)
{
    const int f = rdflag(flag32);
    const int tid = threadIdx.x;
    const int n = blockIdx.x * 256 + tid;

    if (blockIdx.x == 0) {
        for (int i = tid; i < NPAR; i += 256) {
            const void* src; int j;
            if (i < CC)        { src = wS;     j = i; }
            else if (i < 2*CC) { src = wB;     j = i - CC; }
            else               { src = compat; j = i - 2*CC; }
            par[i] = f ? ((const float*)src)[j]
                       : __bfloat162float(((const __hip_bfloat16*)src)[j]);
        }
    }
    {
        float c0, c1, c2;
        if (f) { const float* p = (const float*)img;
                 c0 = p[3*n]; c1 = p[3*n+1]; c2 = p[3*n+2]; }
        else   { const __hip_bfloat16* p = (const __hip_bfloat16*)img;
                 c0 = __bfloat162float(p[3*n]); c1 = __bfloat162float(p[3*n+1]);
                 c2 = __bfloat162float(p[3*n+2]); }
        float ym = (float)(n / WW), xm = (float)(n % WW);
        const float sc = 0.15014029f;   // sqrt(2*L2E/128)
        const float cf = 9.6089787f;    // sqrt(64*L2E)
        featx[8*n + 0] = -L2E * (fmaf(ym, ym, xm*xm) * 0.0078125f
                                 + 32.f * (c0*c0 + c1*c1 + c2*c2));
        featx[8*n + 1] = sc * ym;
        featx[8*n + 2] = sc * xm;
        featx[8*n + 3] = cf * c0;
        featx[8*n + 4] = cf * c1;
        featx[8*n + 5] = cf * c2;
        featx[8*n + 6] = 0.f;
        featx[8*n + 7] = 0.f;
    }

    float v[CC];
    float mx = -1e30f;
    #pragma unroll
    for (int c = 0; c < CC; c++) {
        float uv = f ? ((const float*)u)[n*CC + c]
                     : __bfloat162float(((const __hip_bfloat16*)u)[n*CC + c]);
        uf[n*CC + c] = uv;
        v[c] = uv;
        mx = fmaxf(mx, uv);
    }
    float s = 0.f;
    #pragma unroll
    for (int c = 0; c < CC; c++) { v[c] = fexp(v[c] - mx); s += v[c]; }
    float inv = 1.f / s;
    #pragma unroll
    for (int c = 0; c < CC; c++) {
        pT[(size_t)c*NN + n] = __float2bfloat16(v[c] * inv);
        bil[(size_t)c*NN + n] = 0.f;
    }
}

// ---- blur body (shared by both work kernels)
__device__ __forceinline__ void blur_item(
    int item, float* smem, const __hip_bfloat16* __restrict__ pT,
    float* __restrict__ s2T, int tid)
{
    float* A   = smem;           // up to 52 rows x 96
    float* B2  = smem + 4992;    // 12 x 96
    float* w_s = smem + 6144;    // 21 weights
    const int b2 = item - BLURKEY;
    const int c = b2 % CC;
    const int strip = b2 / CC;
    const int y0 = strip * SROWS;
    const int ylo = (y0 - RS < 0) ? 0 : y0 - RS;
    const int yhi = (y0 + SROWS - 1 + RS > HH - 1) ? HH - 1 : y0 + SROWS - 1 + RS;
    const int nrows = yhi - ylo + 1;

    if (tid <= RS) w_s[tid] = fexp2(-(float)(tid*tid) * (L2E / 18.f));
    const __hip_bfloat16* src = pT + (size_t)c * NN + ylo * WW;
    for (int i = tid; i < nrows * WW; i += 256)
        A[i] = __bfloat162float(src[i]);
    __syncthreads();

    for (int i = tid; i < SROWS * WW; i += 256) {
        const int yo = y0 + i / WW;
        const int x  = i % WW;
        float acc = A[(yo - ylo) * WW + x];
        #pragma unroll
        for (int d = 1; d <= RS; d++) {
            float s = 0.f;
            if (yo - d >= 0)  s += A[(yo - d - ylo) * WW + x];
            if (yo + d < HH)  s += A[(yo + d - ylo) * WW + x];
            acc = fmaf(w_s[d], s, acc);
        }
        B2[i] = acc;
    }
    __syncthreads();

    for (int i = tid; i < SROWS * WW; i += 256) {
        const int r = i / WW, x = i % WW;
        float acc = B2[i];
        #pragma unroll
        for (int d = 1; d <= RS; d++) {
            float s = 0.f;
            if (x - d >= 0)  s += B2[r * WW + x - d];
            if (x + d < WW)  s += B2[r * WW + x + d];
            acc = fmaf(w_s[d], s, acc);
        }
        s2T[(size_t)c * NN + (y0 + r) * WW + x] = acc;
    }
}

// Work kernel, BUILD flavor (iteration 1): computes K fragments, stores them to
// kb in MFMA lane order, and does the iteration-1 MFMA + atomics. tab stride 2:
// [key, slot_base].
__global__ __launch_bounds__(256) void k_workK(
    const __hip_bfloat16* __restrict__ pT, const float* __restrict__ featx,
    float* __restrict__ bil, float* __restrict__ s2T,
    const int* __restrict__ tab, short* __restrict__ kb)
{
    __shared__ float smem[6176];
    const int tid = threadIdx.x;
    const int item = tab[2*blockIdx.x];
    const int base = tab[2*blockIdx.x + 1];

    if (item < BLURKEY) {
        float* lds_h = smem;
        const int wv = tid >> 6, lane = tid & 63;
        const int quad = lane >> 5, lid = lane & 31;
        int ny0, nx0, my0, mx0, dx, T;
        item_geom(item, ny0, nx0, my0, mx0, dx, T);

        int blo = ny0 - T - my0;      blo = blo < 0 ? 0 : blo;
        int bhi = ny0 + 15 + T - my0; bhi = bhi > 23 ? 23 : bhi;
        {   // stage featx rows blo..bhi
            float4* dst = (float4*)lds_h;
            for (int i = blo * 32 + tid; i < (bhi + 1) * 32; i += 256) {
                const int seg = i >> 5, off = i & 31;
                dst[i] = ((const float4*)(featx +
                          (size_t)((my0 + seg) * WW + mx0) * 8))[off];
            }
        }
        __syncthreads();

        int lo, hi;
        wave_range(ny0, my0, T, wv, lo, hi);
        if (lo > hi) return;                    // wave-uniform
        int pre = 0;                            // slot prefix of earlier waves
        for (int wv2 = 0; wv2 < wv; wv2++) {
            int l2, h2; wave_range(ny0, my0, T, wv2, l2, h2);
            if (l2 <= h2) pre += h2 - l2 + 1;
        }
        short* kp = kb + (((size_t)(base + pre)) << 10) + (lane << 3);

        const int row = lid >> 4, col = lid & 15;
        const int n0 = (ny0 + 4*wv + row) * WW + nx0 + col;
        const int n1 = n0 + 2 * WW;
        const float4 g0a = *(const float4*)(featx + (size_t)n0 * 8);
        const float4 g0b = *(const float4*)(featx + (size_t)n0 * 8 + 4);
        const float4 g1a = *(const float4*)(featx + (size_t)n1 * 8);
        const float4 g1b = *(const float4*)(featx + (size_t)n1 * 8 + 4);

        f32x16 acc0, acc1;
        #pragma unroll
        for (int r = 0; r < 16; r++) { acc0[r] = 0.f; acc1[r] = 0.f; }

        int mg = (my0 + lo) * WW + mx0 + quad * 8;
        #pragma unroll 1
        for (int step = lo; step <= hi; step++, mg += WW, kp += 1024) {
            bf16x8 afrag = *(const bf16x8*)(pT + (size_t)lid * NN + mg);
            const float* h = lds_h + (step * 16 + quad * 8) * 8;
            float kb0[8], kb1[8];
            #pragma unroll
            for (int j = 0; j < 8; j++) {
                float4 ha = *(const float4*)(h + j * 8);
                float4 hb = *(const float4*)(h + j * 8 + 4);
                float s0 = g0a.x + ha.x;
                s0 = fmaf(g0a.y, ha.y, s0); s0 = fmaf(g0a.z, ha.z, s0);
                s0 = fmaf(g0a.w, ha.w, s0); s0 = fmaf(g0b.x, hb.x, s0);
                s0 = fmaf(g0b.y, hb.y, s0);
                kb0[j] = fexp2(s0);
                float s1 = g1a.x + ha.x;
                s1 = fmaf(g1a.y, ha.y, s1); s1 = fmaf(g1a.z, ha.z, s1);
                s1 = fmaf(g1a.w, ha.w, s1); s1 = fmaf(g1b.x, hb.x, s1);
                s1 = fmaf(g1b.y, hb.y, s1);
                kb1[j] = fexp2(s1);
            }
            bf16x8 b0, b1;
            #pragma unroll
            for (int j = 0; j < 8; j++) { b0[j] = f2b(kb0[j]); b1[j] = f2b(kb1[j]); }

            *(bf16x8*)kp = b0;                   // coalesced: lane*16B
            *(bf16x8*)(kp + 512) = b1;

            acc0 = __builtin_amdgcn_mfma_f32_32x32x16_bf16(afrag, b0, acc0, 0, 0, 0);
            acc1 = __builtin_amdgcn_mfma_f32_32x32x16_bf16(afrag, b1, acc1, 0, 0, 0);
        }
        #pragma unroll
        for (int r = 0; r < 16; r++) {
            int c = (r & 3) + 8 * (r >> 2) + 4 * quad;
            if (c < CC) {
                atomicAdd(&bil[(size_t)c * NN + n0], acc0[r]);
                atomicAdd(&bil[(size_t)c * NN + n1], acc1[r]);
            }
        }
    } else {
        blur_item(item, smem, pT, s2T, tid);
    }
}

// Work kernel, CACHED flavor (iterations 2..5): streams K fragments back.
// No exp, no LDS, no staging barrier in the bilateral path.
__global__ __launch_bounds__(256) void k_workC(
    const __hip_bfloat16* __restrict__ pT,
    float* __restrict__ bil, float* __restrict__ s2T,
    const int* __restrict__ tab, const short* __restrict__ kb)
{
    __shared__ float smem[6176];
    const int tid = threadIdx.x;
    const int item = tab[2*blockIdx.x];
    const int base = tab[2*blockIdx.x + 1];

    if (item < BLURKEY) {
        const int wv = tid >> 6, lane = tid & 63;
        const int quad = lane >> 5, lid = lane & 31;
        int ny0, nx0, my0, mx0, dx, T;
        item_geom(item, ny0, nx0, my0, mx0, dx, T);
        int lo, hi;
        wave_range(ny0, my0, T, wv, lo, hi);
        if (lo > hi) return;
        int pre = 0;
        for (int wv2 = 0; wv2 < wv; wv2++) {
            int l2, h2; wave_range(ny0, my0, T, wv2, l2, h2);
            if (l2 <= h2) pre += h2 - l2 + 1;
        }
        const short* kp = kb + (((size_t)(base + pre)) << 10) + (lane << 3);

        const int row = lid >> 4, col = lid & 15;
        const int n0 = (ny0 + 4*wv + row) * WW + nx0 + col;
        const int n1 = n0 + 2 * WW;

        f32x16 acc0, acc1;
        #pragma unroll
        for (int r = 0; r < 16; r++) { acc0[r] = 0.f; acc1[r] = 0.f; }

        int mg = (my0 + lo) * WW + mx0 + quad * 8;
        for (int step = lo; step <= hi; step++, mg += WW, kp += 1024) {
            bf16x8 afrag = *(const bf16x8*)(pT + (size_t)lid * NN + mg);
            bf16x8 b0 = *(const bf16x8*)kp;
            bf16x8 b1 = *(const bf16x8*)(kp + 512);
            acc0 = __builtin_amdgcn_mfma_f32_32x32x16_bf16(afrag, b0, acc0, 0, 0, 0);
            acc1 = __builtin_amdgcn_mfma_f32_32x32x16_bf16(afrag, b1, acc1, 0, 0, 0);
        }
        #pragma unroll
        for (int r = 0; r < 16; r++) {
            int c = (r & 3) + 8 * (r >> 2) + 4 * quad;
            if (c < CC) {
                atomicAdd(&bil[(size_t)c * NN + n0], acc0[r]);
                atomicAdd(&bil[(size_t)c * NN + n1], acc1[r]);
            }
        }
    } else {
        blur_item(item, smem, pT, s2T, tid);
    }
}

// Combine + compat + q-update + softmax (unchanged from R3)
__global__ __launch_bounds__(256) void k_update(
    float* __restrict__ bil, const float* __restrict__ s2T,
    const float* __restrict__ uf, const float* __restrict__ par,
    const int* __restrict__ flag32,
    __hip_bfloat16* __restrict__ pT, void* __restrict__ out, int last)
{
    __shared__ float sc[CC*CC + 1];
    __shared__ float sws[CC], swb[CC];
    const int tid = threadIdx.x;
    for (int i = tid; i < CC*CC; i += 256) sc[i] = par[2*CC + i];
    if (tid == 0) sc[CC*CC] = 0.f;
    if (tid < CC) { sws[tid] = par[tid]; swb[tid] = par[CC + tid]; }
    __syncthreads();

    const int half = tid & 1;
    const int n = blockIdx.x * 128 + (tid >> 1);

    float msg[11];
    #pragma unroll
    for (int k = 0; k < 11; k++) {
        const int cp = 2*k + half;
        if (cp < CC) {
            msg[k] = fmaf(s2T[(size_t)cp*NN + n], sws[cp],
                          bil[(size_t)cp*NN + n] * swb[cp]);
            bil[(size_t)cp*NN + n] = 0.f;
        } else msg[k] = 0.f;
    }

    float pw[CC];
    #pragma unroll
    for (int c = 0; c < CC; c++) {
        float a = msg[0] * sc[c*CC + half];
        #pragma unroll
        for (int k = 1; k < 11; k++)
            a = fmaf(msg[k], sc[c*CC + 2*k + half], a);
        pw[c] = a;
    }
    #pragma unroll
    for (int c = 0; c < CC; c++)
        pw[c] += __shfl_xor(pw[c], 1, 64);

    float qv[CC];
    float mx = -1e30f;
    #pragma unroll
    for (int c = 0; c < CC; c++) {
        qv[c] = uf[(size_t)n*CC + c] - pw[c];
        mx = fmaxf(mx, qv[c]);
    }

    if (last) {
        const int is_f32 = rdflag(flag32);
        #pragma unroll
        for (int k = 0; k < 11; k++) {
            const int ce = 2*k, co = (k < 10) ? 2*k + 1 : 0;
            float v = half ? qv[co] : qv[ce];
            const int c = 2*k + half;
            if (c < CC) {
                if (is_f32) ((float*)out)[(size_t)n*CC + c] = v;
                else ((__hip_bfloat16*)out)[(size_t)n*CC + c] = __float2bfloat16(v);
            }
        }
    } else {
        float ex[11]; float ssum = 0.f;
        #pragma unroll
        for (int k = 0; k < 11; k++) {
            const int ce = 2*k, co = (k < 10) ? 2*k + 1 : 0;
            float v = half ? qv[co] : qv[ce];
            float e = fexp(v - mx);
            if (2*k + half < CC) ssum += e;
            ex[k] = e;
        }
        ssum += __shfl_xor(ssum, 1, 64);
        const float inv = 1.f / ssum;
        #pragma unroll
        for (int k = 0; k < 11; k++) {
            const int c = 2*k + half;
            if (c < CC) pT[(size_t)c*NN + n] = __float2bfloat16(ex[k] * inv);
        }
    }
}

extern "C" void kernel_launch(void* const* d_in, const int* in_sizes, int n_in,
                              void* d_out, int out_size, void* d_ws, size_t ws_size,
                              hipStream_t stream)
{
    // ---- static work table: culled survivors, LPT order, K slot bases
    static int h_tab[2 * (NBB + NBLUR)];
    static int h_n = 0;
    static long h_slots = 0;
    if (h_n == 0) {
        struct It { int key; int cost; };
        static It its[NBB + NBLUR];
        int m = 0;
        for (int nt = 0; nt < 36; nt++)
            for (int mc = 0; mc < 24; mc++) {
                const int ny0 = (nt/6)*16, nx0 = (nt%6)*16;
                const int my0 = (mc&3)*24, mx0 = (mc>>2)*16;
                const int dx = (mx0 > nx0+15) ? mx0-(nx0+15)
                             : ((nx0 > mx0+15) ? nx0-(mx0+15) : 0);
                const int lim = TRUNC2 - dx*dx;
                if (lim < 0) continue;
                int T = (int)std::sqrt((double)lim);
                while (T*T > lim) T--;
                while ((T+1)*(T+1) <= lim) T++;
                int cost = 0;
                for (int wv = 0; wv < 4; wv++) {
                    const int by0 = ny0 + 4*wv;
                    int lo = by0 - T - my0;     if (lo < 0)  lo = 0;
                    int hi = by0 + 3 + T - my0; if (hi > 23) hi = 23;
                    if (lo <= hi) cost += hi - lo + 1;
                }
                if (cost == 0) continue;
                its[m].key = (nt << 5) | mc; its[m].cost = cost; m++;
            }
        for (int b = 0; b < NBLUR; b++) { its[m].key = BLURKEY + b; its[m].cost = 20; m++; }
        std::sort(its, its + m, [](const It& a, const It& b) { return a.cost > b.cost; });
        long base = 0;
        for (int i = 0; i < m; i++) {
            h_tab[2*i] = its[i].key;
            h_tab[2*i + 1] = (int)base;
            if (its[i].key < BLURKEY) base += its[i].cost;   // cost == slot count
        }
        h_n = m;
        h_slots = base;                                       // ~51k slots
    }

    float* ws = (float*)d_ws;
    int*   flag32 = (int*)ws;                    // [0..32)
    float* par    = ws + 32;
    float* featx  = ws + 544;                    // NN*8 = 73728 floats
    __hip_bfloat16* pT = (__hip_bfloat16*)(ws + 74272);   // 32*NN bf16 = 147456 floats
    float* uf  = ws + 74272 + 147456;            // NELEM  (= ws+221728)
    float* s2T = uf + NELEM;
    float* bil = s2T + NELEM;
    int*   d_tab = (int*)(bil + NELEM);          // 2*h_n ints
    short* d_kb  = (short*)(ws + 806912);        // 2KB slots, ~102 MB

    const size_t need = 806912ull*4 + (size_t)h_slots * 2048ull;
    const int use_cache = (ws_size >= need);

    hipMemcpyAsync(d_tab, h_tab, 2 * h_n * sizeof(int), hipMemcpyHostToDevice, stream);

    k_sniff<<<32, 256, 0, stream>>>((const unsigned short*)d_in[0], flag32);
    k_prep<<<NN/256, 256, 0, stream>>>(d_in[0], d_in[1], d_in[2], d_in[3], d_in[4],
                                       flag32, uf, featx, par, bil, pT);

    for (int it = 0; it < 5; it++) {
        if (it == 0 || !use_cache)
            k_workK<<<h_n, 256, 0, stream>>>(pT, featx, bil, s2T, d_tab, d_kb);
        else
            k_workC<<<h_n, 256, 0, stream>>>(pT, bil, s2T, d_tab, d_kb);
        k_update<<<NN/128, 256, 0, stream>>>(bil, s2T, uf, par, flag32,
                                             pT, d_out, (it == 4) ? 1 : 0);
    }
}